// Round 6
// baseline (554.792 us; speedup 1.0000x reference)
//
#include <hip/hip_runtime.h>

constexpr int D = 64;
constexpr int BUK_SHIFT = 9;            // 512 dst nodes per bucket
constexpr int BUK_NODES = 1 << BUK_SHIFT;
constexpr int MAX_NBUK = 320;           // supports N <= 163840
constexpr int TILE_E = 4096;            // edges per scatter block (512 thr x 8)

typedef __attribute__((ext_vector_type(8))) short short8;   // 8 bf16 (4 VGPRs)
typedef __attribute__((ext_vector_type(4))) float f32x4;

__device__ inline unsigned short f2bf(float f) {   // RNE f32->bf16
    unsigned int u = __float_as_uint(f);
    u += 0x7FFFu + ((u >> 16) & 1u);
    return (unsigned short)(u >> 16);
}
__device__ inline float bf2f(unsigned short s) {
    return __uint_as_float(((unsigned int)s) << 16);
}

// ---------- 1. histogram of coarse buckets (dst >> BUK_SHIFT) ----------
__global__ __launch_bounds__(256) void k_bucket_hist(const int* __restrict__ ei,
                                                     int* __restrict__ bcount,
                                                     int E, int nbuk) {
    __shared__ int h[MAX_NBUK];
    for (int i = threadIdx.x; i < nbuk; i += blockDim.x) h[i] = 0;
    __syncthreads();
    int stride = gridDim.x * blockDim.x;
    for (int e = blockIdx.x * blockDim.x + threadIdx.x; e < E; e += stride)
        atomicAdd(&h[ei[E + e] >> BUK_SHIFT], 1);
    __syncthreads();
    for (int i = threadIdx.x; i < nbuk; i += blockDim.x)
        if (h[i]) atomicAdd(&bcount[i], h[i]);
}

// ---------- 2. scan bucket counts -> bbase; zero gfill; rowptr[N]=E ----------
__global__ __launch_bounds__(512) void k_scan_buckets(const int* __restrict__ bcount,
                                                      int* __restrict__ bbase,
                                                      int* __restrict__ gfill,
                                                      int* __restrict__ rowptr,
                                                      int nbuk, int N, int E) {
    __shared__ int sc[512];
    int tid = threadIdx.x;
    int v = (tid < nbuk) ? bcount[tid] : 0;
    sc[tid] = v;
    __syncthreads();
    for (int off = 1; off < 512; off <<= 1) {
        int t = (tid >= off) ? sc[tid - off] : 0;
        __syncthreads();
        sc[tid] += t;
        __syncthreads();
    }
    if (tid < nbuk) { bbase[tid] = sc[tid] - v; gfill[tid] = 0; }
    if (tid == 0) { bbase[nbuk] = E; rowptr[N] = E; }
}

// ---------- 3. scatter edges into coarse buckets (packed u32) ----------
__global__ __launch_bounds__(512) void k_bucket_scatter(const int* __restrict__ ei,
                                                        const int* __restrict__ bbase,
                                                        int* __restrict__ gfill,
                                                        unsigned int* __restrict__ packed,
                                                        int E, int nbuk) {
    __shared__ int hist[MAX_NBUK], base[MAX_NBUK], fil[MAX_NBUK];
    const int tid = threadIdx.x;
    for (int i = tid; i < nbuk; i += 512) hist[i] = 0;
    __syncthreads();

    const int t0 = blockIdx.x * TILE_E;
    int bk[8];
    unsigned int vv[8];
#pragma unroll
    for (int j = 0; j < 8; ++j) {
        int e = t0 + tid + j * 512;
        bk[j] = -1;
        if (e < E) {
            int src = ei[e];
            int dst = ei[E + e];
            bk[j] = dst >> BUK_SHIFT;
            vv[j] = ((unsigned int)(dst & (BUK_NODES - 1)) << 18) | (unsigned int)src;
            atomicAdd(&hist[bk[j]], 1);
        }
    }
    __syncthreads();
    for (int i = tid; i < nbuk; i += 512) {
        if (hist[i]) base[i] = atomicAdd(&gfill[i], hist[i]);
        fil[i] = 0;
    }
    __syncthreads();
#pragma unroll
    for (int j = 0; j < 8; ++j) {
        if (bk[j] >= 0) {
            int b = bk[j];
            int pos = bbase[b] + base[b] + atomicAdd(&fil[b], 1);
            packed[pos] = vv[j];
        }
    }
}

// ---------- 4. per-bucket: local hist -> rowptr, dinv, ordered csr_src ----------
__global__ __launch_bounds__(256) void k_build_csr(const unsigned int* __restrict__ packed,
                                                   const int* __restrict__ bbase,
                                                   int* __restrict__ rowptr,
                                                   float* __restrict__ dinv,
                                                   int* __restrict__ csr_src,
                                                   int N) {
    __shared__ int hist[BUK_NODES], rp[BUK_NODES], fil[BUK_NODES];
    const int b = blockIdx.x;
    const int s = bbase[b], t = bbase[b + 1];
    const int tid = threadIdx.x;
    for (int i = tid; i < BUK_NODES; i += 256) hist[i] = 0;
    __syncthreads();
    for (int e = s + tid; e < t; e += 256)
        atomicAdd(&hist[packed[e] >> 18], 1);
    __syncthreads();
    if (tid == 0) {
        int run = 0;
        for (int i = 0; i < BUK_NODES; ++i) { rp[i] = run; run += hist[i]; }
    }
    __syncthreads();
    const int dbase = b << BUK_SHIFT;
    for (int ld = tid; ld < BUK_NODES; ld += 256) {
        int d = dbase + ld;
        if (d < N) {
            rowptr[d] = s + rp[ld];
            dinv[d] = rsqrtf((float)(hist[ld] + 1));   // +1 self-loop
        }
        fil[ld] = 0;
    }
    __syncthreads();
    for (int e = s + tid; e < t; e += 256) {
        unsigned int v = packed[e];
        int ld = v >> 18;
        int pos = s + rp[ld] + atomicAdd(&fil[ld], 1);
        csr_src[pos] = (int)(v & 0x3FFFFu);
    }
}

// ------- layer-0 MFMA GEMM: hs16 = bf16((x0 @ W)*dinv), acc = x0 -------
__global__ __launch_bounds__(256) void k_gemm_mfma(const float* __restrict__ u,
                                                   const float* __restrict__ it,
                                                   int U,
                                                   const float* __restrict__ W,
                                                   const float* __restrict__ dinv,
                                                   unsigned short* __restrict__ hs16,
                                                   float* __restrict__ acc,
                                                   int N) {
    const int lane = threadIdx.x & 63;
    const int g = lane >> 4;
    const int lr = lane & 15;

    short8 bf[4][2];
#pragma unroll
    for (int ct = 0; ct < 4; ++ct)
#pragma unroll
        for (int kb = 0; kb < 2; ++kb) {
            short8 v;
            int c = ct * 16 + lr;
#pragma unroll
            for (int e = 0; e < 4; ++e) {
                int k0 = kb * 32 + g * 4 + e;
                int k1 = k0 + 16;
                v[e]     = (short)f2bf(W[k0 * D + c]);
                v[e + 4] = (short)f2bf(W[k1 * D + c]);
            }
            bf[ct][kb] = v;
        }

    const int wid = blockIdx.x * (blockDim.x >> 6) + (threadIdx.x >> 6);
    const int nw = gridDim.x * (blockDim.x >> 6);

    for (int rb = wid * 16; rb < N; rb += nw * 16) {
        int row = rb + lr;                     // A-operand row for this lane
        bool ok = (row < N);
        const float* xr = nullptr;
        if (ok) xr = (row < U) ? (u + (size_t)row * D)
                               : (it + (size_t)(row - U) * D);
        short8 af[2];
#pragma unroll
        for (int kb = 0; kb < 2; ++kb) {
            float4 q0 = ok ? *(const float4*)(xr + kb * 32 + g * 4)
                           : float4{0.f, 0.f, 0.f, 0.f};
            float4 q1 = ok ? *(const float4*)(xr + kb * 32 + 16 + g * 4)
                           : float4{0.f, 0.f, 0.f, 0.f};
            if (ok) {   // acc = x0 (exact copy, same coverage as the tile)
                *(float4*)(acc + (size_t)row * D + kb * 32 + g * 4) = q0;
                *(float4*)(acc + (size_t)row * D + kb * 32 + 16 + g * 4) = q1;
            }
            short8 v;
            v[0] = (short)f2bf(q0.x); v[1] = (short)f2bf(q0.y);
            v[2] = (short)f2bf(q0.z); v[3] = (short)f2bf(q0.w);
            v[4] = (short)f2bf(q1.x); v[5] = (short)f2bf(q1.y);
            v[6] = (short)f2bf(q1.z); v[7] = (short)f2bf(q1.w);
            af[kb] = v;
        }

        float di[4];
#pragma unroll
        for (int r = 0; r < 4; ++r) {
            int ro = rb + g * 4 + r;
            di[r] = (ro < N) ? dinv[ro] : 0.f;
        }

#pragma unroll
        for (int ct = 0; ct < 4; ++ct) {
            f32x4 a = {0.f, 0.f, 0.f, 0.f};
            a = __builtin_amdgcn_mfma_f32_16x16x32_bf16(af[0], bf[ct][0], a, 0, 0, 0);
            a = __builtin_amdgcn_mfma_f32_16x16x32_bf16(af[1], bf[ct][1], a, 0, 0, 0);
#pragma unroll
            for (int r = 0; r < 4; ++r) {
                int ro = rb + g * 4 + r;
                if (ro < N)
                    hs16[(size_t)ro * D + ct * 16 + lr] = f2bf(a[r] * di[r]);
            }
        }
    }
}

// ------- fused layer: val = agg(hs_cur)+b; acc update; hs_next = bf16((val@Wn)*dinv) -------
// block = 4 waves = 16 dst rows; wave w owns local rows w*4..w*4+3.
template <bool LAST>
__global__ __launch_bounds__(256) void k_fused_layer(const int* __restrict__ rowptr,
                                                     const int* __restrict__ csr_src,
                                                     const unsigned short* __restrict__ hs_cur,
                                                     const float* __restrict__ dinv,
                                                     const float* __restrict__ b,
                                                     const float* __restrict__ Wn,
                                                     float* __restrict__ acc,
                                                     unsigned short* __restrict__ hs_next,
                                                     float scale, int N) {
    __shared__ float val[16][65];
    const int tid = threadIdx.x;
    const int lane = tid & 63;
    const int w = tid >> 6;               // wave id = col-tile ct
    const int g = lane >> 4, lr = lane & 15;
    const int rb = blockIdx.x * 16;

    short8 bfr[2];
    if (!LAST) {                          // B-frag for this wave's col-tile
        int c = w * 16 + lr;
#pragma unroll
        for (int kb = 0; kb < 2; ++kb) {
            short8 v;
#pragma unroll
            for (int e = 0; e < 4; ++e) {
                int k0 = kb * 32 + g * 4 + e;
                v[e]     = (short)f2bf(Wn[k0 * D + c]);
                v[e + 4] = (short)f2bf(Wn[(k0 + 16) * D + c]);
            }
            bfr[kb] = v;
        }
    }

    const float bl = b[lane];

    int row[4], end[4];
    int e0, e1, e2, e3;
    float s[4];
#pragma unroll
    for (int j = 0; j < 4; ++j) {
        row[j] = rb + w * 4 + j;
        if (row[j] < N) {
            int bg = rowptr[row[j]];
            end[j] = rowptr[row[j] + 1];
            if (j == 0) e0 = bg; else if (j == 1) e1 = bg;
            else if (j == 2) e2 = bg; else e3 = bg;
            s[j] = bf2f(hs_cur[(size_t)row[j] * D + lane]);   // self-loop
        } else {
            end[j] = 0;
            if (j == 0) e0 = 0; else if (j == 1) e1 = 0;
            else if (j == 2) e2 = 0; else e3 = 0;
            s[j] = 0.f;
        }
    }

    // interleaved pair-loop: up to 8 gathers in flight
    while ((e0 + 2 <= end[0]) | (e1 + 2 <= end[1]) |
           (e2 + 2 <= end[2]) | (e3 + 2 <= end[3])) {
        if (e0 + 2 <= end[0]) {
            int a0 = csr_src[e0], a1 = csr_src[e0 + 1]; e0 += 2;
            s[0] += bf2f(hs_cur[(size_t)a0 * D + lane]) + bf2f(hs_cur[(size_t)a1 * D + lane]);
        }
        if (e1 + 2 <= end[1]) {
            int a0 = csr_src[e1], a1 = csr_src[e1 + 1]; e1 += 2;
            s[1] += bf2f(hs_cur[(size_t)a0 * D + lane]) + bf2f(hs_cur[(size_t)a1 * D + lane]);
        }
        if (e2 + 2 <= end[2]) {
            int a0 = csr_src[e2], a1 = csr_src[e2 + 1]; e2 += 2;
            s[2] += bf2f(hs_cur[(size_t)a0 * D + lane]) + bf2f(hs_cur[(size_t)a1 * D + lane]);
        }
        if (e3 + 2 <= end[3]) {
            int a0 = csr_src[e3], a1 = csr_src[e3 + 1]; e3 += 2;
            s[3] += bf2f(hs_cur[(size_t)a0 * D + lane]) + bf2f(hs_cur[(size_t)a1 * D + lane]);
        }
    }
    if (e0 < end[0]) s[0] += bf2f(hs_cur[(size_t)csr_src[e0] * D + lane]);
    if (e1 < end[1]) s[1] += bf2f(hs_cur[(size_t)csr_src[e1] * D + lane]);
    if (e2 < end[2]) s[2] += bf2f(hs_cur[(size_t)csr_src[e2] * D + lane]);
    if (e3 < end[3]) s[3] += bf2f(hs_cur[(size_t)csr_src[e3] * D + lane]);

#pragma unroll
    for (int j = 0; j < 4; ++j) {
        if (row[j] < N) {
            float v = fmaf(s[j], dinv[row[j]], bl);
            size_t idx = (size_t)row[j] * D + lane;
            if (LAST) acc[idx] = (acc[idx] + v) * scale;
            else      acc[idx] = acc[idx] + v;
            if (!LAST) val[w * 4 + j][lane] = v;
        }
    }

    if (!LAST) {
        __syncthreads();
        // A-frags from LDS (row = lr, k = kb*32 + g*4 + e (+16))
        short8 af[2];
#pragma unroll
        for (int kb = 0; kb < 2; ++kb) {
            short8 v;
#pragma unroll
            for (int e = 0; e < 4; ++e) {
                v[e]     = (short)f2bf(val[lr][kb * 32 + g * 4 + e]);
                v[e + 4] = (short)f2bf(val[lr][kb * 32 + 16 + g * 4 + e]);
            }
            af[kb] = v;
        }
        f32x4 a = {0.f, 0.f, 0.f, 0.f};
        a = __builtin_amdgcn_mfma_f32_16x16x32_bf16(af[0], bfr[0], a, 0, 0, 0);
        a = __builtin_amdgcn_mfma_f32_16x16x32_bf16(af[1], bfr[1], a, 0, 0, 0);
#pragma unroll
        for (int r = 0; r < 4; ++r) {
            int ro = rb + g * 4 + r;
            if (ro < N)
                hs_next[(size_t)ro * D + w * 16 + lr] = f2bf(a[r] * dinv[ro]);
        }
    }
}

extern "C" void kernel_launch(void* const* d_in, const int* in_sizes, int n_in,
                              void* d_out, int out_size, void* d_ws, size_t ws_size,
                              hipStream_t stream) {
    const int* ei      = (const int*)d_in[0];
    const float* uemb  = (const float*)d_in[1];
    const float* iemb  = (const float*)d_in[2];
    const float* Ws    = (const float*)d_in[3];
    const float* bs    = (const float*)d_in[4];

    const int E = in_sizes[0] / 2;
    const int U = in_sizes[1] / D;
    const int I = in_sizes[2] / D;
    const int N = U + I;
    const int ND = N * D;
    const int nbuk = (N + BUK_NODES - 1) >> BUK_SHIFT;

    unsigned short* hsA = (unsigned short*)d_ws;          // [N, D] bf16
    unsigned short* hsB = hsA + ND;                       // [N, D] bf16
    float* dinv    = (float*)(hsB + ND);                  // [N]
    int*   csr_src = (int*)(dinv + N);                    // [E]
    unsigned int* packed = (unsigned int*)(csr_src + E);  // [E]
    int*   rowptr  = (int*)(packed + E);                  // [N+1]
    int*   bcount  = rowptr + N + 1;                      // [nbuk]
    int*   bbase   = bcount + MAX_NBUK;                   // [nbuk+1]
    int*   gfill   = bbase + MAX_NBUK + 1;                // [nbuk]

    float* acc = (float*)d_out;                           // [N, D]

    // ---- build CSR ----
    hipMemsetAsync(bcount, 0, nbuk * sizeof(int), stream);
    k_bucket_hist<<<512, 256, 0, stream>>>(ei, bcount, E, nbuk);
    k_scan_buckets<<<1, 512, 0, stream>>>(bcount, bbase, gfill, rowptr, nbuk, N, E);
    k_bucket_scatter<<<(E + TILE_E - 1) / TILE_E, 512, 0, stream>>>(ei, bbase, gfill,
                                                                   packed, E, nbuk);
    k_build_csr<<<nbuk, 256, 0, stream>>>(packed, bbase, rowptr, dinv, csr_src, N);

    // ---- layer 0 GEMM (+ acc = x0) ----
    k_gemm_mfma<<<1024, 256, 0, stream>>>(uemb, iemb, U, Ws, dinv, hsA, acc, N);

    // ---- fused layers ----
    const int nblk = (N + 15) / 16;
    k_fused_layer<false><<<nblk, 256, 0, stream>>>(rowptr, csr_src, hsA, dinv,
                                                   bs, Ws + (size_t)1 * D * D,
                                                   acc, hsB, 1.0f, N);
    k_fused_layer<false><<<nblk, 256, 0, stream>>>(rowptr, csr_src, hsB, dinv,
                                                   bs + D, Ws + (size_t)2 * D * D,
                                                   acc, hsA, 1.0f, N);
    k_fused_layer<true><<<nblk, 256, 0, stream>>>(rowptr, csr_src, hsA, dinv,
                                                  bs + 2 * D, nullptr,
                                                  acc, nullptr, 0.25f, N);
}

// Round 7
// 391.115 us; speedup vs baseline: 1.4185x; 1.4185x over previous
//
#include <hip/hip_runtime.h>

constexpr int D = 64;
constexpr int BUK_SHIFT = 9;            // 512 dst nodes per bucket
constexpr int BUK_NODES = 1 << BUK_SHIFT;
constexpr int MAX_NBUK = 320;           // supports N <= 163840
constexpr int TILE_E = 4096;            // edges per scatter block (512 thr x 8)

typedef __attribute__((ext_vector_type(8))) short short8;   // 8 bf16 (4 VGPRs)
typedef __attribute__((ext_vector_type(4))) float f32x4;

__device__ inline unsigned short f2bf(float f) {   // RNE f32->bf16
    unsigned int u = __float_as_uint(f);
    u += 0x7FFFu + ((u >> 16) & 1u);
    return (unsigned short)(u >> 16);
}
__device__ inline float bf2f(unsigned short s) {
    return __uint_as_float(((unsigned int)s) << 16);
}

// ---------- 1. histogram of coarse buckets (dst >> BUK_SHIFT) ----------
__global__ __launch_bounds__(256) void k_bucket_hist(const int* __restrict__ ei,
                                                     int* __restrict__ bcount,
                                                     int E, int nbuk) {
    __shared__ int h[MAX_NBUK];
    for (int i = threadIdx.x; i < nbuk; i += blockDim.x) h[i] = 0;
    __syncthreads();
    int stride = gridDim.x * blockDim.x;
    for (int e = blockIdx.x * blockDim.x + threadIdx.x; e < E; e += stride)
        atomicAdd(&h[ei[E + e] >> BUK_SHIFT], 1);
    __syncthreads();
    for (int i = threadIdx.x; i < nbuk; i += blockDim.x)
        if (h[i]) atomicAdd(&bcount[i], h[i]);
}

// ---------- 2. scan bucket counts -> bbase; zero gfill; rowptr[N]=E ----------
__global__ __launch_bounds__(512) void k_scan_buckets(const int* __restrict__ bcount,
                                                      int* __restrict__ bbase,
                                                      int* __restrict__ gfill,
                                                      int* __restrict__ rowptr,
                                                      int nbuk, int N, int E) {
    __shared__ int sc[512];
    int tid = threadIdx.x;
    int v = (tid < nbuk) ? bcount[tid] : 0;
    sc[tid] = v;
    __syncthreads();
    for (int off = 1; off < 512; off <<= 1) {
        int t = (tid >= off) ? sc[tid - off] : 0;
        __syncthreads();
        sc[tid] += t;
        __syncthreads();
    }
    if (tid < nbuk) { bbase[tid] = sc[tid] - v; gfill[tid] = 0; }
    if (tid == 0) { bbase[nbuk] = E; rowptr[N] = E; }
}

// ---------- 3. scatter edges into coarse buckets (packed u32) ----------
__global__ __launch_bounds__(512) void k_bucket_scatter(const int* __restrict__ ei,
                                                        const int* __restrict__ bbase,
                                                        int* __restrict__ gfill,
                                                        unsigned int* __restrict__ packed,
                                                        int E, int nbuk) {
    __shared__ int hist[MAX_NBUK], base[MAX_NBUK], fil[MAX_NBUK];
    const int tid = threadIdx.x;
    for (int i = tid; i < nbuk; i += 512) hist[i] = 0;
    __syncthreads();

    const int t0 = blockIdx.x * TILE_E;
    int bk[8];
    unsigned int vv[8];
#pragma unroll
    for (int j = 0; j < 8; ++j) {
        int e = t0 + tid + j * 512;
        bk[j] = -1;
        if (e < E) {
            int src = ei[e];
            int dst = ei[E + e];
            bk[j] = dst >> BUK_SHIFT;
            vv[j] = ((unsigned int)(dst & (BUK_NODES - 1)) << 18) | (unsigned int)src;
            atomicAdd(&hist[bk[j]], 1);
        }
    }
    __syncthreads();
    for (int i = tid; i < nbuk; i += 512) {
        if (hist[i]) base[i] = atomicAdd(&gfill[i], hist[i]);
        fil[i] = 0;
    }
    __syncthreads();
#pragma unroll
    for (int j = 0; j < 8; ++j) {
        if (bk[j] >= 0) {
            int b = bk[j];
            int pos = bbase[b] + base[b] + atomicAdd(&fil[b], 1);
            packed[pos] = vv[j];
        }
    }
}

// ---------- 4. per-bucket: local hist -> rowptr, dinv, ordered csr_src ----------
__global__ __launch_bounds__(256) void k_build_csr(const unsigned int* __restrict__ packed,
                                                   const int* __restrict__ bbase,
                                                   int* __restrict__ rowptr,
                                                   float* __restrict__ dinv,
                                                   int* __restrict__ csr_src,
                                                   int N) {
    __shared__ int hist[BUK_NODES], rp[BUK_NODES], fil[BUK_NODES];
    const int b = blockIdx.x;
    const int s = bbase[b], t = bbase[b + 1];
    const int tid = threadIdx.x;
    for (int i = tid; i < BUK_NODES; i += 256) hist[i] = 0;
    __syncthreads();
    for (int e = s + tid; e < t; e += 256)
        atomicAdd(&hist[packed[e] >> 18], 1);
    __syncthreads();
    if (tid == 0) {
        int run = 0;
        for (int i = 0; i < BUK_NODES; ++i) { rp[i] = run; run += hist[i]; }
    }
    __syncthreads();
    const int dbase = b << BUK_SHIFT;
    for (int ld = tid; ld < BUK_NODES; ld += 256) {
        int d = dbase + ld;
        if (d < N) {
            rowptr[d] = s + rp[ld];
            dinv[d] = rsqrtf((float)(hist[ld] + 1));   // +1 self-loop
        }
        fil[ld] = 0;
    }
    __syncthreads();
    for (int e = s + tid; e < t; e += 256) {
        unsigned int v = packed[e];
        int ld = v >> 18;
        int pos = s + rp[ld] + atomicAdd(&fil[ld], 1);
        csr_src[pos] = (int)(v & 0x3FFFFu);
    }
}

// ------- MFMA GEMM: hs_out = bf16((xin @ W)*dinv); layer 0 also acc = x0 -------
// wave handles 16 rows x 64 cols. A/B frag (16x16x32 bf16):
//   elems 0..3: k = kb*32 +      (lane>>4)*4 + e ; elems 4..7: +16
// D: col = lane&15, row = (lane>>4)*4 + reg.
template <bool F32IN>
__global__ __launch_bounds__(256) void k_gemm(const float* __restrict__ u,
                                              const float* __restrict__ it,
                                              int U,
                                              const unsigned short* __restrict__ xin16,
                                              const float* __restrict__ W,
                                              const float* __restrict__ dinv,
                                              unsigned short* __restrict__ hs_out,
                                              float* __restrict__ acc,
                                              int N) {
    const int lane = threadIdx.x & 63;
    const int g = lane >> 4;
    const int lr = lane & 15;

    short8 bf[4][2];
#pragma unroll
    for (int ct = 0; ct < 4; ++ct)
#pragma unroll
        for (int kb = 0; kb < 2; ++kb) {
            short8 v;
            int c = ct * 16 + lr;
#pragma unroll
            for (int e = 0; e < 4; ++e) {
                int k0 = kb * 32 + g * 4 + e;
                v[e]     = (short)f2bf(W[k0 * D + c]);
                v[e + 4] = (short)f2bf(W[(k0 + 16) * D + c]);
            }
            bf[ct][kb] = v;
        }

    const int wid = blockIdx.x * (blockDim.x >> 6) + (threadIdx.x >> 6);
    const int nw = gridDim.x * (blockDim.x >> 6);

    for (int rb = wid * 16; rb < N; rb += nw * 16) {
        int row = rb + lr;                     // A-operand row for this lane
        bool ok = (row < N);
        short8 af[2];
        if (F32IN) {
            const float* xr = nullptr;
            if (ok) xr = (row < U) ? (u + (size_t)row * D)
                                   : (it + (size_t)(row - U) * D);
#pragma unroll
            for (int kb = 0; kb < 2; ++kb) {
                float4 q0 = ok ? *(const float4*)(xr + kb * 32 + g * 4)
                               : float4{0.f, 0.f, 0.f, 0.f};
                float4 q1 = ok ? *(const float4*)(xr + kb * 32 + 16 + g * 4)
                               : float4{0.f, 0.f, 0.f, 0.f};
                if (ok) {   // acc = x0
                    *(float4*)(acc + (size_t)row * D + kb * 32 + g * 4) = q0;
                    *(float4*)(acc + (size_t)row * D + kb * 32 + 16 + g * 4) = q1;
                }
                short8 v;
                v[0] = (short)f2bf(q0.x); v[1] = (short)f2bf(q0.y);
                v[2] = (short)f2bf(q0.z); v[3] = (short)f2bf(q0.w);
                v[4] = (short)f2bf(q1.x); v[5] = (short)f2bf(q1.y);
                v[6] = (short)f2bf(q1.z); v[7] = (short)f2bf(q1.w);
                af[kb] = v;
            }
        } else {
            const unsigned short* xr = xin16 + (size_t)row * D;
#pragma unroll
            for (int kb = 0; kb < 2; ++kb) {
                short4 q0 = ok ? *(const short4*)(xr + kb * 32 + g * 4)
                               : short4{0, 0, 0, 0};
                short4 q1 = ok ? *(const short4*)(xr + kb * 32 + 16 + g * 4)
                               : short4{0, 0, 0, 0};
                short8 v;
                v[0] = q0.x; v[1] = q0.y; v[2] = q0.z; v[3] = q0.w;
                v[4] = q1.x; v[5] = q1.y; v[6] = q1.z; v[7] = q1.w;
                af[kb] = v;
            }
        }

        float di[4];
#pragma unroll
        for (int r = 0; r < 4; ++r) {
            int ro = rb + g * 4 + r;
            di[r] = (ro < N) ? dinv[ro] : 0.f;
        }

#pragma unroll
        for (int ct = 0; ct < 4; ++ct) {
            f32x4 a = {0.f, 0.f, 0.f, 0.f};
            a = __builtin_amdgcn_mfma_f32_16x16x32_bf16(af[0], bf[ct][0], a, 0, 0, 0);
            a = __builtin_amdgcn_mfma_f32_16x16x32_bf16(af[1], bf[ct][1], a, 0, 0, 0);
#pragma unroll
            for (int r = 0; r < 4; ++r) {
                int ro = rb + g * 4 + r;
                if (ro < N)
                    hs_out[(size_t)ro * D + ct * 16 + lr] = f2bf(a[r] * di[r]);
            }
        }
    }
}

// ------- val = dinv*(hs[d] + sum hs[src]) + b; acc update; val16 = bf16(val) -------
template <bool LAST>
__global__ __launch_bounds__(256) void k_aggregate(const int* __restrict__ rowptr,
                                                   const int* __restrict__ csr_src,
                                                   const unsigned short* __restrict__ hs16,
                                                   const float* __restrict__ dinv,
                                                   const float* __restrict__ b,
                                                   unsigned short* __restrict__ val16,
                                                   float* __restrict__ acc,
                                                   float scale, int N) {
    int w = (int)((blockIdx.x * (size_t)blockDim.x + threadIdx.x) >> 6);
    int lane = threadIdx.x & 63;
    if (w >= N) return;
    int beg = rowptr[w], end = rowptr[w + 1];
    float s0 = bf2f(hs16[(size_t)w * D + lane]);   // self-loop (already * dinv)
    float s1 = 0.f, s2 = 0.f, s3 = 0.f;
    float s4 = 0.f, s5 = 0.f, s6 = 0.f, s7 = 0.f;
    int e = beg;
    for (; e + 8 <= end; e += 8) {
        int i0 = csr_src[e + 0], i1 = csr_src[e + 1];
        int i2 = csr_src[e + 2], i3 = csr_src[e + 3];
        int i4 = csr_src[e + 4], i5 = csr_src[e + 5];
        int i6 = csr_src[e + 6], i7 = csr_src[e + 7];
        s0 += bf2f(hs16[(size_t)i0 * D + lane]);
        s1 += bf2f(hs16[(size_t)i1 * D + lane]);
        s2 += bf2f(hs16[(size_t)i2 * D + lane]);
        s3 += bf2f(hs16[(size_t)i3 * D + lane]);
        s4 += bf2f(hs16[(size_t)i4 * D + lane]);
        s5 += bf2f(hs16[(size_t)i5 * D + lane]);
        s6 += bf2f(hs16[(size_t)i6 * D + lane]);
        s7 += bf2f(hs16[(size_t)i7 * D + lane]);
    }
    if (e + 4 <= end) {
        int i0 = csr_src[e + 0], i1 = csr_src[e + 1];
        int i2 = csr_src[e + 2], i3 = csr_src[e + 3];
        s0 += bf2f(hs16[(size_t)i0 * D + lane]);
        s1 += bf2f(hs16[(size_t)i1 * D + lane]);
        s2 += bf2f(hs16[(size_t)i2 * D + lane]);
        s3 += bf2f(hs16[(size_t)i3 * D + lane]);
        e += 4;
    }
    for (; e < end; ++e) s0 += bf2f(hs16[(size_t)csr_src[e] * D + lane]);

    float sum = ((s0 + s1) + (s2 + s3)) + ((s4 + s5) + (s6 + s7));
    float val = fmaf(sum, dinv[w], b[lane]);
    size_t idx = (size_t)w * D + lane;
    if (LAST) {
        acc[idx] = (acc[idx] + val) * scale;
    } else {
        acc[idx] = acc[idx] + val;
        val16[idx] = f2bf(val);
    }
}

extern "C" void kernel_launch(void* const* d_in, const int* in_sizes, int n_in,
                              void* d_out, int out_size, void* d_ws, size_t ws_size,
                              hipStream_t stream) {
    const int* ei      = (const int*)d_in[0];
    const float* uemb  = (const float*)d_in[1];
    const float* iemb  = (const float*)d_in[2];
    const float* Ws    = (const float*)d_in[3];
    const float* bs    = (const float*)d_in[4];

    const int E = in_sizes[0] / 2;
    const int U = in_sizes[1] / D;
    const int I = in_sizes[2] / D;
    const int N = U + I;
    const int ND = N * D;
    const int nbuk = (N + BUK_NODES - 1) >> BUK_SHIFT;

    unsigned short* X = (unsigned short*)d_ws;            // [N, D] bf16 (hs)
    unsigned short* Y = X + ND;                           // [N, D] bf16 (val)
    float* dinv    = (float*)(Y + ND);                    // [N]
    int*   csr_src = (int*)(dinv + N);                    // [E]
    unsigned int* packed = (unsigned int*)(csr_src + E);  // [E]
    int*   rowptr  = (int*)(packed + E);                  // [N+1]
    int*   bcount  = rowptr + N + 1;                      // [nbuk]
    int*   bbase   = bcount + MAX_NBUK;                   // [nbuk+1]
    int*   gfill   = bbase + MAX_NBUK + 1;                // [nbuk]

    float* acc = (float*)d_out;                           // [N, D]

    // ---- build CSR ----
    hipMemsetAsync(bcount, 0, nbuk * sizeof(int), stream);
    k_bucket_hist<<<512, 256, 0, stream>>>(ei, bcount, E, nbuk);
    k_scan_buckets<<<1, 512, 0, stream>>>(bcount, bbase, gfill, rowptr, nbuk, N, E);
    k_bucket_scatter<<<(E + TILE_E - 1) / TILE_E, 512, 0, stream>>>(ei, bbase, gfill,
                                                                   packed, E, nbuk);
    k_build_csr<<<nbuk, 256, 0, stream>>>(packed, bbase, rowptr, dinv, csr_src, N);

    // ---- layer 0 GEMM (+ acc = x0): emb -> X = hs1 ----
    k_gemm<true><<<1024, 256, 0, stream>>>(uemb, iemb, U, nullptr, Ws, dinv, X, acc, N);

    const int nagg = (N + 3) / 4;
    // layer 1: X -> Y (val1 bf16), acc += val1
    k_aggregate<false><<<nagg, 256, 0, stream>>>(rowptr, csr_src, X, dinv, bs,
                                                 Y, acc, 1.0f, N);
    // gemm: Y -> X = hs2
    k_gemm<false><<<1024, 256, 0, stream>>>(nullptr, nullptr, U, Y,
                                            Ws + (size_t)1 * D * D, dinv, X, acc, N);
    // layer 2: X -> Y (val2), acc += val2
    k_aggregate<false><<<nagg, 256, 0, stream>>>(rowptr, csr_src, X, dinv, bs + D,
                                                 Y, acc, 1.0f, N);
    // gemm: Y -> X = hs3
    k_gemm<false><<<1024, 256, 0, stream>>>(nullptr, nullptr, U, Y,
                                            Ws + (size_t)2 * D * D, dinv, X, acc, N);
    // layer 3 (last): X -> acc = (acc + val3) * 0.25
    k_aggregate<true><<<nagg, 256, 0, stream>>>(rowptr, csr_src, X, dinv, bs + 2 * D,
                                                nullptr, acc, 0.25f, N);
}